// Round 3
// baseline (76.572 us; speedup 1.0000x reference)
//
#include <hip/hip_runtime.h>

typedef __bf16 bf16;
typedef __attribute__((ext_vector_type(8))) __bf16 bf16x8;
typedef __attribute__((ext_vector_type(4))) float f32x4;

#define EPS_ 1e-6f
constexpr int B_ = 16, N_ = 256, D_ = 4, K_ = 10, C_ = 100;
constexpr int CP_ = 112;                    // padded c rows in xkT workspace
constexpr size_t XKT_ELEMS = (size_t)B_ * K_ * CP_ * N_;   // 4,587,520 bf16

// ---------------------------------------------------------------------------
// Kernel 0: W (f32 [100][100]) -> Wp (bf16 [112][128], zero-padded).
// ---------------------------------------------------------------------------
__global__ void wcvt(const float* __restrict__ W, bf16* __restrict__ Wp)
{
    int idx = blockIdx.x * 256 + threadIdx.x;      // grid covers 112*128
    if (idx < 112 * 128) {
        int c = idx >> 7, j = idx & 127;
        Wp[idx] = (bf16)((c < C_ && j < C_) ? W[c * C_ + j] : 0.0f);
    }
}

// ---------------------------------------------------------------------------
// Kernel 1: xkT[b,k][c][m] = sum_j W[c,j]*x[b,m,k*C+j] + bias[c]  (bf16 out)
//   A = Wp (c x j, bf16, L1-hot, zero-padded so no edge branches),
//   B = x slice (j x m, cvt in regs). Grid (4,10,16)=640 blocks, 4 waves;
//   wave owns one 16-wide m tile, all 7 c tiles, fully unrolled K.
// ---------------------------------------------------------------------------
__global__ __launch_bounds__(256) void xkT_mfma(
    const float* __restrict__ x, const bf16* __restrict__ Wp,
    const float* __restrict__ bias, bf16* __restrict__ xkT)
{
    const int mh = blockIdx.x, k = blockIdx.y, b = blockIdx.z;
    const int tid = threadIdx.x;
    const int w = tid >> 6, l = tid & 63, l15 = l & 15, g = l >> 4;

    const int m = mh * 64 + w * 16 + l15;          // this lane's B column
    const float* xp = x + ((size_t)(b * N_ + m) * K_ + k) * C_;

    f32x4 acc[7];
    #pragma unroll
    for (int ct = 0; ct < 7; ++ct)
        #pragma unroll
        for (int r = 0; r < 4; ++r) {
            int c = ct * 16 + g * 4 + r;
            acc[ct][r] = (c < C_) ? bias[c] : 0.0f;
        }

    #pragma unroll
    for (int ks = 0; ks < 4; ++ks) {
        const int jb = ks * 32 + g * 8;
        bf16x8 bfr;
        #pragma unroll
        for (int i = 0; i < 8; ++i) bfr[i] = (bf16)0.0f;
        if (jb + 8 <= C_) {
            float4 x0 = *(const float4*)(xp + jb);
            float4 x1 = *(const float4*)(xp + jb + 4);
            bfr[0] = (bf16)x0.x; bfr[1] = (bf16)x0.y; bfr[2] = (bf16)x0.z; bfr[3] = (bf16)x0.w;
            bfr[4] = (bf16)x1.x; bfr[5] = (bf16)x1.y; bfr[6] = (bf16)x1.z; bfr[7] = (bf16)x1.w;
        } else if (jb < C_) {                       // jb == 96
            float4 x0 = *(const float4*)(xp + jb);
            bfr[0] = (bf16)x0.x; bfr[1] = (bf16)x0.y; bfr[2] = (bf16)x0.z; bfr[3] = (bf16)x0.w;
        }
        #pragma unroll
        for (int ct = 0; ct < 7; ++ct) {
            bf16x8 af = *(const bf16x8*)(Wp + (size_t)(ct * 16 + l15) * 128 + jb);
            acc[ct] = __builtin_amdgcn_mfma_f32_16x16x32_bf16(af, bfr, acc[ct], 0, 0, 0);
        }
    }

    bf16* op = xkT + (size_t)(b * K_ + k) * CP_ * N_;
    #pragma unroll
    for (int ct = 0; ct < 7; ++ct)
        #pragma unroll
        for (int r = 0; r < 4; ++r)
            op[(size_t)(ct * 16 + g * 4 + r) * N_ + m] = (bf16)acc[ct][r];
}

// ---------------------------------------------------------------------------
// Kernel 2: out[b,k][c][n] = sum_m ag[n,m] * xk[m,c]
//   Block = (b, k, n-quarter, c-half). xkT c-half staged in LDS (32 KB,
//   XOR-swizzled, conflict-free ds_read_b128). A-fragments (gaussian) built
//   in registers with depth-2 software pipeline. Zero barriers in main loop.
// Grid 1280 blocks (XCD-swizzled), 256 threads = 4 waves.
// ---------------------------------------------------------------------------
__global__ __launch_bounds__(256) void gauss_agg_mfma(
    const float* __restrict__ adj, const float* __restrict__ pseudo,
    const float* __restrict__ mu, const float* __restrict__ sigma,
    const bf16* __restrict__ xkT, float* __restrict__ out)
{
    __shared__ __align__(16) char lds[64 * 512];   // 64 rows x 512B, swizzled

    // XCD-aware decode: b pinned per XCD; (b,k,nq,ch) each hit once.
    const int bid  = blockIdx.x;                   // 0..1279
    const int xcd  = bid & 7, slot = bid >> 3;     // slot 0..159
    const int b    = xcd + 8 * (slot / 80);
    const int rr   = slot % 80;
    const int k    = rr / 8, t = rr % 8, nq = t >> 1, ch = t & 1;
    const int cbase = ch * 64;

    const int tid = threadIdx.x;
    const int w = tid >> 6, l = tid & 63, l15 = l & 15, g = l >> 4;
    const int n_tile = nq * 64 + w * 16;

    // ---- stage xkT c-half into LDS (linear global -> swizzled LDS) ----
    const bf16* xs = xkT + (size_t)(b * K_ + k) * CP_ * N_;
    #pragma unroll
    for (int pass = 0; pass < 8; ++pass) {
        int idx = pass * 256 + tid;                // 2048 chunks of 16B
        int row = idx >> 5, j = idx & 31;
        int cr  = cbase + row;
        int4 v = {0, 0, 0, 0};
        if (cr < CP_) v = *(const int4*)((const char*)xs + (size_t)cr * 512 + j * 16);
        *(int4*)(lds + row * 512 + ((j ^ (row & 7)) * 16)) = v;
    }

    float muv[4], coef[4];
    #pragma unroll
    for (int d = 0; d < 4; ++d) {
        float s = sigma[k * 4 + d];
        coef[d] = -0.5f / (EPS_ + s * s);
        muv[d]  = mu[k * 4 + d];
    }

    const int n_a = n_tile + l15;                  // A-fragment row (n)
    const float* adj_row = adj + ((size_t)b * N_ + n_a) * N_;
    const float* ps_row  = pseudo + ((size_t)(b * N_ + n_a) * N_) * 4;

    __syncthreads();                               // LDS ready

    f32x4 acc[4];
    #pragma unroll
    for (int ct = 0; ct < 4; ++ct)
        #pragma unroll
        for (int r = 0; r < 4; ++r) acc[ct][r] = 0.0f;

    struct Frag { float4 p[8]; float4 a0, a1; };
    auto load = [&](Frag& f, int ks) {
        const int m0 = ks * 32 + g * 8;
        f.a0 = *(const float4*)(adj_row + m0);
        f.a1 = *(const float4*)(adj_row + m0 + 4);
        #pragma unroll
        for (int i = 0; i < 8; ++i)
            f.p[i] = *(const float4*)(ps_row + (size_t)(m0 + i) * 4);
    };
    auto compute = [&](const Frag& f, int ks) {
        const float av[8] = {f.a0.x, f.a0.y, f.a0.z, f.a0.w,
                             f.a1.x, f.a1.y, f.a1.z, f.a1.w};
        bf16x8 af;
        #pragma unroll
        for (int i = 0; i < 8; ++i) {
            float dx = f.p[i].x - muv[0], dy = f.p[i].y - muv[1];
            float dz = f.p[i].z - muv[2], dw = f.p[i].w - muv[3];
            float s = coef[0] * dx * dx + coef[1] * dy * dy
                    + coef[2] * dz * dz + coef[3] * dw * dw;
            af[i] = (bf16)(av[i] * __expf(s));
        }
        #pragma unroll
        for (int ct = 0; ct < 4; ++ct) {
            const int row_l = ct * 16 + l15;
            bf16x8 bfr = *(const bf16x8*)(lds + row_l * 512
                            + (((ks * 4 + g) ^ (l15 & 7)) * 16));
            acc[ct] = __builtin_amdgcn_mfma_f32_16x16x32_bf16(af, bfr, acc[ct], 0, 0, 0);
        }
    };

    Frag fA, fB;
    load(fA, 0);
    load(fB, 1);
    #pragma unroll
    for (int kp = 0; kp < 4; ++kp) {
        compute(fA, 2 * kp);
        if (kp < 3) load(fA, 2 * kp + 2);
        compute(fB, 2 * kp + 1);
        if (kp < 3) load(fB, 2 * kp + 3);
    }

    // ---- store: out[(b*K+k)*C*N + c*N + n], float4 over 4 consecutive n ----
    float* ob = out + (size_t)(b * K_ + k) * C_ * N_;
    #pragma unroll
    for (int ct = 0; ct < 4; ++ct) {
        int c = cbase + ct * 16 + l15;
        if (c < C_) {
            float4 v = {acc[ct][0], acc[ct][1], acc[ct][2], acc[ct][3]};
            *(float4*)(ob + (size_t)c * N_ + n_tile + g * 4) = v;
        }
    }
}

extern "C" void kernel_launch(void* const* d_in, const int* in_sizes, int n_in,
                              void* d_out, int out_size, void* d_ws, size_t ws_size,
                              hipStream_t stream)
{
    const float* x      = (const float*)d_in[0];
    const float* adj    = (const float*)d_in[1];
    const float* pseudo = (const float*)d_in[2];
    const float* mu     = (const float*)d_in[3];
    const float* sigma  = (const float*)d_in[4];
    const float* W      = (const float*)d_in[5];
    const float* bias   = (const float*)d_in[6];
    float* out = (float*)d_out;

    bf16* xkT = (bf16*)d_ws;                              // 9.2 MB
    bf16* Wp  = (bf16*)((char*)d_ws + XKT_ELEMS * 2);     // 28.7 KB

    hipLaunchKernelGGL(wcvt, dim3((112 * 128 + 255) / 256), dim3(256), 0, stream, W, Wp);
    hipLaunchKernelGGL(xkT_mfma, dim3(4, K_, B_), dim3(256), 0, stream, x, Wp, bias, xkT);
    hipLaunchKernelGGL(gauss_agg_mfma, dim3(B_ * K_ * 8), dim3(256), 0, stream,
                       adj, pseudo, mu, sigma, xkT, out);
}

// Round 4
// 51.165 us; speedup vs baseline: 1.4966x; 1.4966x over previous
//
#include <hip/hip_runtime.h>

typedef __bf16 bf16;
typedef __attribute__((ext_vector_type(4)))  __bf16 bf16x4;
typedef __attribute__((ext_vector_type(8)))  __bf16 bf16x8;
typedef __attribute__((ext_vector_type(4)))  float  f32x4;
typedef __attribute__((ext_vector_type(16))) float  f32x16;

constexpr int B_ = 16, N_ = 256, K_ = 10, C_ = 100, CP_ = 112;
constexpr float NL2E = -0.7213475204444817f;            // -0.5*log2(e)
constexpr size_t XKT_ELEMS = (size_t)B_ * K_ * CP_ * N_; // 4,587,520 bf16
constexpr size_t AG_OFF    = XKT_ELEMS;                  // ag follows xkT in ws

// ---------------------------------------------------------------------------
// Kernel A ("prep"), heterogeneous grid of 1664 blocks:
//  blocks [0,640):   xkT[b,k][c(112)][m] = sum_j W[c,j]*x[b,m,k*C+j] + bias
//                    (MFMA 16x16x32; W converted to LDS bf16 [112][136])
//  blocks [640,1664): ag[b,k][n][m] = adj * exp(-0.5 sum_d (p-mu)^2/(eps+s^2))
//                    pseudo read ONCE, all 10 k computed per element
//                    (s = gamma_k + sum_d alpha_k,d p_d^2 + beta_k,d p_d,
//                     coefs pre-folded with log2(e), exp2 hardware op)
//  Both sub-grids XCD-swizzled so slices of batch b live in XCD (b&7) L2.
// ---------------------------------------------------------------------------
__global__ __launch_bounds__(256) void prep(
    const float* __restrict__ x, const float* __restrict__ adj,
    const float* __restrict__ pseudo, const float* __restrict__ mu,
    const float* __restrict__ sigma, const float* __restrict__ W,
    const float* __restrict__ bias, bf16* __restrict__ ws)
{
    __shared__ __align__(16) char smem[112 * 136 * 2];
    const int bid = blockIdx.x, tid = threadIdx.x;

    if (bid < 640) {
        // ------------------- xkT GEMM part -------------------
        bf16* Wl = (bf16*)smem;                       // [112][136] bf16
        #pragma unroll 1
        for (int idx = tid; idx < 112 * 136; idx += 256) {
            int c = idx / 136, j = idx - c * 136;
            Wl[idx] = (bf16)((c < C_ && j < C_) ? W[c * C_ + j] : 0.0f);
        }
        __syncthreads();

        const int xcd = bid & 7, s = bid >> 3;        // s: 0..79
        const int b  = xcd + 8 * (s / 40);
        const int rr = s % 40, kk = rr >> 2, mh = rr & 3;
        const int w = tid >> 6, l = tid & 63, l15 = l & 15, g = l >> 4;
        const int m = mh * 64 + w * 16 + l15;
        const float* xp = x + ((size_t)(b * N_ + m) * K_ + kk) * C_;

        f32x4 acc[7];
        #pragma unroll
        for (int ct = 0; ct < 7; ++ct)
            #pragma unroll
            for (int r = 0; r < 4; ++r) {
                int c = ct * 16 + g * 4 + r;
                acc[ct][r] = (c < C_) ? bias[c] : 0.0f;
            }

        #pragma unroll
        for (int ks = 0; ks < 4; ++ks) {
            const int jb = ks * 32 + g * 8;
            bf16x8 bfr;
            #pragma unroll
            for (int i = 0; i < 8; ++i) bfr[i] = (bf16)0.0f;
            if (jb + 8 <= C_) {
                float4 x0 = *(const float4*)(xp + jb);
                float4 x1 = *(const float4*)(xp + jb + 4);
                bfr[0]=(bf16)x0.x; bfr[1]=(bf16)x0.y; bfr[2]=(bf16)x0.z; bfr[3]=(bf16)x0.w;
                bfr[4]=(bf16)x1.x; bfr[5]=(bf16)x1.y; bfr[6]=(bf16)x1.z; bfr[7]=(bf16)x1.w;
            } else if (jb < C_) {                     // jb == 96
                float4 x0 = *(const float4*)(xp + jb);
                bfr[0]=(bf16)x0.x; bfr[1]=(bf16)x0.y; bfr[2]=(bf16)x0.z; bfr[3]=(bf16)x0.w;
            }
            #pragma unroll
            for (int ct = 0; ct < 7; ++ct) {
                bf16x8 af = *(const bf16x8*)(Wl + (size_t)(ct * 16 + l15) * 136 + jb);
                acc[ct] = __builtin_amdgcn_mfma_f32_16x16x32_bf16(af, bfr, acc[ct], 0, 0, 0);
            }
        }

        bf16* op = ws + (size_t)(b * K_ + kk) * CP_ * N_;
        #pragma unroll
        for (int ct = 0; ct < 7; ++ct)
            #pragma unroll
            for (int r = 0; r < 4; ++r)
                op[(size_t)(ct * 16 + g * 4 + r) * N_ + m] = (bf16)acc[ct][r];
    } else {
        // ------------------- gaussian ag part -------------------
        float* cf = (float*)smem;                     // [K][9]: alpha4, beta4, gamma
        if (tid < K_) {
            float ga = 0.0f;
            #pragma unroll
            for (int d = 0; d < 4; ++d) {
                float sg = sigma[tid * 4 + d];
                float al = NL2E / (1e-6f + sg * sg);
                float mv = mu[tid * 4 + d];
                cf[tid * 9 + d]     = al;
                cf[tid * 9 + 4 + d] = -2.0f * al * mv;
                ga += al * mv * mv;
            }
            cf[tid * 9 + 8] = ga;
        }
        __syncthreads();

        const int a = bid - 640;                      // 0..1023
        const int xcd = a & 7, u = a >> 3;            // u: 0..127
        const int b = xcd + 8 * (u & 1);
        const int n = (u >> 1) * 4 + (tid >> 6);
        const int m = (tid & 63) * 4;

        const float* pp = pseudo + ((size_t)(b * N_ + n) * N_ + m) * 4;
        float4 p0 = *(const float4*)(pp + 0);
        float4 p1 = *(const float4*)(pp + 4);
        float4 p2 = *(const float4*)(pp + 8);
        float4 p3 = *(const float4*)(pp + 12);
        float4 av = *(const float4*)(adj + (size_t)(b * N_ + n) * N_ + m);

        float4 q0 = {p0.x*p0.x, p0.y*p0.y, p0.z*p0.z, p0.w*p0.w};
        float4 q1 = {p1.x*p1.x, p1.y*p1.y, p1.z*p1.z, p1.w*p1.w};
        float4 q2 = {p2.x*p2.x, p2.y*p2.y, p2.z*p2.z, p2.w*p2.w};
        float4 q3 = {p3.x*p3.x, p3.y*p3.y, p3.z*p3.z, p3.w*p3.w};

        bf16* agb = ws + AG_OFF;
        #pragma unroll
        for (int k = 0; k < K_; ++k) {
            float a0 = cf[k*9+0], a1 = cf[k*9+1], a2 = cf[k*9+2], a3 = cf[k*9+3];
            float b0 = cf[k*9+4], b1 = cf[k*9+5], b2 = cf[k*9+6], b3 = cf[k*9+7];
            float ga = cf[k*9+8];

            float s0 = ga + a0*q0.x + b0*p0.x + a1*q0.y + b1*p0.y
                          + a2*q0.z + b2*p0.z + a3*q0.w + b3*p0.w;
            float s1 = ga + a0*q1.x + b0*p1.x + a1*q1.y + b1*p1.y
                          + a2*q1.z + b2*p1.z + a3*q1.w + b3*p1.w;
            float s2 = ga + a0*q2.x + b0*p2.x + a1*q2.y + b1*p2.y
                          + a2*q2.z + b2*p2.z + a3*q2.w + b3*p2.w;
            float s3 = ga + a0*q3.x + b0*p3.x + a1*q3.y + b1*p3.y
                          + a2*q3.z + b2*p3.z + a3*q3.w + b3*p3.w;

            float g0 = __builtin_amdgcn_exp2f(s0) * av.x;
            float g1 = __builtin_amdgcn_exp2f(s1) * av.y;
            float g2 = __builtin_amdgcn_exp2f(s2) * av.z;
            float g3 = __builtin_amdgcn_exp2f(s3) * av.w;

            bf16x4 o = {(bf16)g0, (bf16)g1, (bf16)g2, (bf16)g3};
            *(bf16x4*)(agb + ((size_t)(b * K_ + k) * N_ + n) * N_ + m) = o;
        }
    }
}

// ---------------------------------------------------------------------------
// Kernel B: out[b,k][c][n] = sum_m ag[n,m] * xk[m,c]   (pure streaming GEMM)
//   MFMA 32x32x16 bf16: A = ag (n x m), B = xkT rows (c x m), D (n x c).
//   Block = (b, k, n64-tile): 4 waves; wave w: n32 = (w&1), c-pair = (w>>1).
//   c-tile 3 covers c 96..127: rows 100..111 are zeros in ws; 112..127 read
//   into the ag region (allocated, garbage) and feed only never-stored cols.
// Grid 640 XCD-swizzled blocks, 256 threads.
// ---------------------------------------------------------------------------
__global__ __launch_bounds__(256) void agg_gemm(
    const bf16* __restrict__ ws, float* __restrict__ out)
{
    const int bid = blockIdx.x;
    const int xcd = bid & 7, s = bid >> 3;            // s: 0..79
    const int b  = xcd + 8 * (s / 40);
    const int rr = s % 40, kk = rr >> 2, nh = rr & 3;
    const int tid = threadIdx.x;
    const int w = tid >> 6, l = tid & 63, l31 = l & 31, h = l >> 5;
    const int n32 = nh * 64 + (w & 1) * 32;
    const int ct0 = (w >> 1) * 2;

    const bf16* xk = ws + (size_t)(b * K_ + kk) * CP_ * N_;
    const bf16* ag = ws + AG_OFF + ((size_t)(b * K_ + kk) * N_ + n32) * N_;

    const bf16* arow  = ag + (size_t)l31 * N_;
    const bf16* brow0 = xk + (size_t)(ct0 * 32 + l31) * N_;
    const bf16* brow1 = brow0 + 32 * N_;

    f32x16 acc0, acc1;
    #pragma unroll
    for (int i = 0; i < 16; ++i) { acc0[i] = 0.0f; acc1[i] = 0.0f; }

    #pragma unroll
    for (int ks = 0; ks < 16; ++ks) {
        const int m0 = ks * 16 + h * 8;
        bf16x8 af = *(const bf16x8*)(arow  + m0);
        bf16x8 b0 = *(const bf16x8*)(brow0 + m0);
        bf16x8 b1 = *(const bf16x8*)(brow1 + m0);
        acc0 = __builtin_amdgcn_mfma_f32_32x32x16_bf16(af, b0, acc0, 0, 0, 0);
        acc1 = __builtin_amdgcn_mfma_f32_32x32x16_bf16(af, b1, acc1, 0, 0, 0);
    }

    float* ob = out + (size_t)(b * K_ + kk) * C_ * N_;
    #pragma unroll
    for (int t = 0; t < 2; ++t) {
        const f32x16 acc = t ? acc1 : acc0;
        const int c = (ct0 + t) * 32 + l31;
        if (c < C_) {
            #pragma unroll
            for (int q = 0; q < 4; ++q) {
                // D row = (reg&3) + 8*(reg>>2) + 4*(lane>>5), reg = 4q+r
                float4 v = {acc[4*q+0], acc[4*q+1], acc[4*q+2], acc[4*q+3]};
                *(float4*)(ob + (size_t)c * N_ + n32 + 8 * q + 4 * h) = v;
            }
        }
    }
}

extern "C" void kernel_launch(void* const* d_in, const int* in_sizes, int n_in,
                              void* d_out, int out_size, void* d_ws, size_t ws_size,
                              hipStream_t stream)
{
    const float* x      = (const float*)d_in[0];
    const float* adj    = (const float*)d_in[1];
    const float* pseudo = (const float*)d_in[2];
    const float* mu     = (const float*)d_in[3];
    const float* sigma  = (const float*)d_in[4];
    const float* W      = (const float*)d_in[5];
    const float* bias   = (const float*)d_in[6];
    float* out = (float*)d_out;
    bf16* ws   = (bf16*)d_ws;   // xkT: 9.18 MB @0, ag: 20.97 MB @ +XKT_ELEMS

    hipLaunchKernelGGL(prep, dim3(1664), dim3(256), 0, stream,
                       x, adj, pseudo, mu, sigma, W, bias, ws);
    hipLaunchKernelGGL(agg_gemm, dim3(640), dim3(256), 0, stream, ws, out);
}